// Round 9
// baseline (217.631 us; speedup 1.0000x reference)
//
#include <hip/hip_runtime.h>
#include <hip/hip_bf16.h>

typedef __hip_bfloat16 bf16;
typedef __attribute__((ext_vector_type(8))) short short8;
typedef __attribute__((ext_vector_type(4))) float f32x4;

// ---------------- sizes ----------------
#define Bsz   16
#define Tn    512
#define SEG   32
#define CD    256
#define DI    512
#define DS    16
#define DCONV 4
#define BT    (Bsz*Tn)   // 8192
#define NPART 32         // hp partial copies

// ---------------- helpers ----------------
__device__ __forceinline__ float erf_fast(float x) {
  float ax = fabsf(x);
  float t = 1.0f / (1.0f + 0.3275911f * ax);
  float p = t * (0.254829592f + t * (-0.284496736f + t * (1.421413741f +
            t * (-1.453152027f + t * 1.061405429f))));
  float r = 1.0f - p * __expf(-ax * ax);
  return copysignf(r, x);
}
__device__ __forceinline__ float gelu_f(float x) {
  return 0.5f * x * (1.0f + erf_fast(x * 0.7071067811865476f));
}
__device__ __forceinline__ float silu_f(float x) {
  return x / (1.0f + __expf(-x));
}
__device__ __forceinline__ float softplus_f(float x) {
  return fmaxf(x, 0.0f) + __logf(1.0f + __expf(-fabsf(x)));
}
__device__ __forceinline__ float bfu(unsigned short u) {
  return __uint_as_float(((unsigned int)u) << 16);
}
__device__ __forceinline__ unsigned short f2bfu(float x) {
  bf16 h = __float2bfloat16(x);
  return *(unsigned short*)&h;
}
__device__ __forceinline__ float block_sum256(float v, float* red) {
  int tid = threadIdx.x;
  #pragma unroll
  for (int off = 32; off > 0; off >>= 1) v += __shfl_down(v, off, 64);
  __syncthreads();
  if ((tid & 63) == 0) red[tid >> 6] = v;
  __syncthreads();
  return red[0] + red[1] + red[2] + red[3];
}

// ---------------- K0: weight prep + aux path ----------------
__global__ __launch_bounds__(256) void prep_kernel(
    const float* __restrict__ aux, const float* __restrict__ apw,
    const float* __restrict__ g, const float* __restrict__ bb,
    const float* __restrict__ in_w, const float* __restrict__ xpw,
    const float* __restrict__ cpw,
    bf16* __restrict__ w_in, bf16* __restrict__ wpad, bf16* __restrict__ cpwT,
    float* __restrict__ haux)
{
  __shared__ float red[4];
  int i = blockIdx.x * 256 + threadIdx.x;
  if (i < 262144) {
    int e = i & 7, lane = (i >> 3) & 63, k0 = (i >> 9) & 7, nb = i >> 12;
    int fr = lane & 15, q = lane >> 4;
    w_in[i] = __float2bfloat16(in_w[(size_t)(nb * 16 + fr) * 256 + k0 * 32 + q * 8 + e]);
  } else if (i < 294912) {
    int o = i - 262144;      // 0..32767
    int e = o & 7, lane = (o >> 3) & 63, k0 = (o >> 9) & 15, nb = o >> 13;
    int fr = lane & 15, q = lane >> 4;
    int row = nb * 16 + fr, k = k0 * 32 + q * 8 + e;
    float v = 0.f;
    if (row < 32)       v = xpw[(1 + row) * 512 + k];
    else if (row == 32) v = xpw[k];
    wpad[o] = __float2bfloat16(v);
  } else {
    int o = i - 294912;      // 0..8191
    int k = o >> 8, j = o & 255;
    cpwT[o] = __float2bfloat16(cpw[j * 32 + k]);
  }
  if (blockIdx.x < 16) {
    int b = blockIdx.x, j = threadIdx.x;
    float acc = 0.f;
    #pragma unroll
    for (int k = 0; k < 14; ++k)
      acc += aux[b * 14 + k] * apw[j * 14 + k];
    float s1 = block_sum256(acc, red);
    float s2 = block_sum256(acc * acc, red);
    float mean = s1 * (1.f / 256.f);
    float var  = s2 * (1.f / 256.f) - mean * mean;
    float xn = (acc - mean) * rsqrtf(var + 1e-5f) * g[j] + bb[j];
    haux[b * 256 + j] = gelu_f(xn);
  }
}

// ---------------- K1: rows + LNs + in_proj MFMA (512 thr, 8 waves) ----------
// x half -> xbf[t][512]; z half -> zT[(b*16+dgrp)*512 + t][32] (scan-tiled).
__global__ __launch_bounds__(512) void row_inproj_kernel(
    const float* __restrict__ cir, const bf16* __restrict__ cpwT,
    const float* __restrict__ cg, const float* __restrict__ cb,
    const float* __restrict__ mg, const float* __restrict__ mb,
    const float* __restrict__ haux, const bf16* __restrict__ w_in,
    bf16* __restrict__ xbf, bf16* __restrict__ zTg,
    float* __restrict__ hp_part)
{
  __shared__ float hps[8][256];
  __shared__ __align__(16) unsigned short xns[16][264];
  int tid = threadIdx.x;
  int wave = tid >> 6, lane = tid & 63;
  int r0 = blockIdx.x * 16 + wave * 2;
  int b = blockIdx.x >> 5;
  int j0 = lane * 4;

  float vj[2][4] = {};
  for (int c = 0; c < 8; ++c) {
    float xk[2][4];
    #pragma unroll
    for (int r4 = 0; r4 < 2; ++r4) {
      float4 xv = ((const float4*)(cir + (size_t)(r0 + r4) * SEG))[c];
      xk[r4][0] = xv.x; xk[r4][1] = xv.y; xk[r4][2] = xv.z; xk[r4][3] = xv.w;
    }
    #pragma unroll
    for (int kk = 0; kk < 4; ++kk) {
      int k = c * 4 + kk;
      uint2 wv = *(const uint2*)((const unsigned short*)cpwT + k * 256 + j0);
      float w0 = __uint_as_float(wv.x << 16);
      float w1 = __uint_as_float(wv.x & 0xffff0000u);
      float w2 = __uint_as_float(wv.y << 16);
      float w3 = __uint_as_float(wv.y & 0xffff0000u);
      #pragma unroll
      for (int r4 = 0; r4 < 2; ++r4) {
        float xv = xk[r4][kk];
        vj[r4][0] += xv * w0; vj[r4][1] += xv * w1;
        vj[r4][2] += xv * w2; vj[r4][3] += xv * w3;
      }
    }
  }
  float s[2], q2[2];
  #pragma unroll
  for (int r4 = 0; r4 < 2; ++r4) {
    s[r4]  = vj[r4][0] + vj[r4][1] + vj[r4][2] + vj[r4][3];
    q2[r4] = vj[r4][0]*vj[r4][0] + vj[r4][1]*vj[r4][1]
           + vj[r4][2]*vj[r4][2] + vj[r4][3]*vj[r4][3];
  }
  #pragma unroll
  for (int off = 32; off > 0; off >>= 1) {
    #pragma unroll
    for (int r4 = 0; r4 < 2; ++r4) {
      s[r4]  += __shfl_xor(s[r4],  off, 64);
      q2[r4] += __shfl_xor(q2[r4], off, 64);
    }
  }
  float4 cgv = *(const float4*)(cg + j0);
  float4 cbv = *(const float4*)(cb + j0);
  float4 hxv = *(const float4*)(haux + b * 256 + j0);
  float hv[2][4];
  float hs[2], hq[2];
  #pragma unroll
  for (int r4 = 0; r4 < 2; ++r4) {
    float mean = s[r4] * (1.f/256.f);
    float var  = q2[r4] * (1.f/256.f) - mean * mean;
    float inv  = rsqrtf(var + 1e-5f);
    float g0 = gelu_f((vj[r4][0] - mean) * inv * cgv.x + cbv.x) + hxv.x;
    float g1 = gelu_f((vj[r4][1] - mean) * inv * cgv.y + cbv.y) + hxv.y;
    float g2 = gelu_f((vj[r4][2] - mean) * inv * cgv.z + cbv.z) + hxv.z;
    float g3 = gelu_f((vj[r4][3] - mean) * inv * cgv.w + cbv.w) + hxv.w;
    hv[r4][0] = g0; hv[r4][1] = g1; hv[r4][2] = g2; hv[r4][3] = g3;
    hs[r4] = g0 + g1 + g2 + g3;
    hq[r4] = g0*g0 + g1*g1 + g2*g2 + g3*g3;
  }
  #pragma unroll
  for (int off = 32; off > 0; off >>= 1) {
    #pragma unroll
    for (int r4 = 0; r4 < 2; ++r4) {
      hs[r4] += __shfl_xor(hs[r4], off, 64);
      hq[r4] += __shfl_xor(hq[r4], off, 64);
    }
  }
  float4 mgv = *(const float4*)(mg + j0);
  float4 mbv = *(const float4*)(mb + j0);
  #pragma unroll
  for (int r4 = 0; r4 < 2; ++r4) {
    float m2  = hs[r4] * (1.f/256.f);
    float v2  = hq[r4] * (1.f/256.f) - m2 * m2;
    float inv2 = rsqrtf(v2 + 1e-5f);
    unsigned int lo = (unsigned int)f2bfu((hv[r4][0] - m2) * inv2 * mgv.x + mbv.x) |
                      ((unsigned int)f2bfu((hv[r4][1] - m2) * inv2 * mgv.y + mbv.y) << 16);
    unsigned int hi = (unsigned int)f2bfu((hv[r4][2] - m2) * inv2 * mgv.z + mbv.z) |
                      ((unsigned int)f2bfu((hv[r4][3] - m2) * inv2 * mgv.w + mbv.w) << 16);
    uint2 pk; pk.x = lo; pk.y = hi;
    *(uint2*)&xns[wave * 2 + r4][j0] = pk;
  }
  #pragma unroll
  for (int q = 0; q < 4; ++q)
    hps[wave][j0 + q] = hv[0][q] + hv[1][q];
  __syncthreads();
  if (tid < 256) {
    int j = tid;
    float part = hps[0][j] + hps[1][j] + hps[2][j] + hps[3][j]
               + hps[4][j] + hps[5][j] + hps[6][j] + hps[7][j];
    hp_part[(size_t)(blockIdx.x & (NPART - 1)) * 4096 + b * 256 + j] =
        part * (1.f / 512.f);
  }
  // ---- in_proj MFMA from LDS: M=16, N=1024 (wave slice 128), K=256 ----
  {
    int fr = lane & 15, quad = lane >> 4;
    int rbase = blockIdx.x * 16;
    int tl0 = (blockIdx.x & 31) * 16 + quad * 4;
    const short* Wp = (const short*)w_in;
    unsigned short* xp = (unsigned short*)xbf;
    unsigned short* zp = (unsigned short*)zTg;
    #pragma unroll
    for (int nt = 0; nt < 8; ++nt) {
      int nb = wave * 8 + nt;
      f32x4 acc = {0.f, 0.f, 0.f, 0.f};
      #pragma unroll
      for (int k0 = 0; k0 < 8; ++k0) {
        int ka = k0 * 32 + quad * 8;
        short8 a = *(const short8*)&xns[fr][ka];
        short8 bb8 = *(const short8*)(Wp + (((size_t)nb * 8 + k0) * 64 + lane) * 8);
        acc = __builtin_amdgcn_mfma_f32_16x16x32_bf16(a, bb8, acc, 0, 0, 0);
      }
      int n = nb * 16 + fr;
      int crow = quad * 4;
      if (nb < 32) {        // x half (wave-uniform)
        #pragma unroll
        for (int i = 0; i < 4; ++i)
          xp[(size_t)(rbase + crow + i) * 512 + n] = f2bfu(acc[i]);
      } else {              // z half -> scan-tiled zT
        int d = n - 512, dg = d >> 5, d2 = d & 31;
        size_t base = ((size_t)(b * 16 + dg) * 512 + tl0) * 32 + d2;
        #pragma unroll
        for (int i = 0; i < 4; ++i)
          zp[base + (size_t)i * 32] = f2bfu(acc[i]);
      }
    }
  }
}

// ---------------- K2: conv + x_proj MFMA -> ssm, xcT (LDS-staged x tile) ----
__global__ __launch_bounds__(512) void conv_xproj_kernel(
    const bf16* __restrict__ xbf, const bf16* __restrict__ wpad,
    const float* __restrict__ cw, const float* __restrict__ cbv,
    float* __restrict__ ssm, bf16* __restrict__ xcT)
{
  __shared__ __align__(16) unsigned short xst[35][512];
  __shared__ __align__(16) unsigned short xcs[32][520];
  int c = blockIdx.x, b = blockIdx.y;
  int t0 = c * 32;
  int tid = threadIdx.x;
  const unsigned short* xzp = (const unsigned short*)xbf;

  // ---- Phase 0: coalesced stage of rows t0-3 .. t0+31 (35 x 512 bf16) ----
  for (int it = tid; it < 2240; it += 512) {
    int row = it >> 6, c8 = it & 63;
    int t = t0 - 3 + row;
    uint4 v = make_uint4(0u, 0u, 0u, 0u);
    if (t >= 0)
      v = *(const uint4*)(xzp + ((size_t)((b << 9) + t)) * 512 + c8 * 8);
    *(uint4*)&xst[row][c8 * 8] = v;
  }
  __syncthreads();

  // ---- Phase A: depthwise conv + silu from LDS, 1 d per thread ----
  {
    int d = tid;
    float4 w = *(const float4*)(cw + d * 4);
    float cbd = cbv[d];
    float pa = bfu(xst[0][d]), pb = bfu(xst[1][d]), pc = bfu(xst[2][d]);
    #pragma unroll
    for (int i = 0; i < 32; ++i) {
      float x = bfu(xst[3 + i][d]);
      float a = cbd + w.x * pa + w.y * pb + w.z * pc + w.w * x;
      pa = pb; pb = pc; pc = x;
      xcs[i][d] = f2bfu(silu_f(a));
    }
  }
  __syncthreads();

  // ---- Phase C: write xc tile to scan-tiled xcT (coalesced 64B/thread) ----
  {
    int dg = tid >> 5, tl = tid & 31;
    uint4* dst = (uint4*)((unsigned short*)xcT +
                          (((size_t)(b * 16 + dg)) * 512 + t0 + tl) * 32);
    const uint4* src = (const uint4*)&xcs[tl][dg * 32];
    dst[0] = src[0]; dst[1] = src[1]; dst[2] = src[2]; dst[3] = src[3];
  }

  // ---- Phase B: x_proj MFMA from LDS: M=32 (2 halves), N=64, K=512 ----
  {
    int wave = tid >> 6, lane = tid & 63;
    int fr = lane & 15, quad = lane >> 4;
    int mh = wave >> 2;                 // m-half
    int nb = wave & 3;
    int n0 = nb * 16;
    f32x4 acc = {0.f, 0.f, 0.f, 0.f};
    const short* Wp = (const short*)wpad;
    #pragma unroll
    for (int k0 = 0; k0 < 16; ++k0) {
      int ka = k0 * 32 + quad * 8;
      short8 a = *(const short8*)&xcs[mh * 16 + fr][ka];
      short8 b8 = *(const short8*)(Wp + (((size_t)nb * 16 + k0) * 64 + lane) * 8);
      acc = __builtin_amdgcn_mfma_f32_16x16x32_bf16(a, b8, acc, 0, 0, 0);
    }
    int ccol = lane & 15, crow = quad * 4;
    #pragma unroll
    for (int i = 0; i < 4; ++i)
      ssm[((size_t)((b << 9) + t0 + mh * 16 + crow + i)) * 64 + n0 + ccol] = acc[i];
  }
}

// ---------------- K3: full-sequence scan, 2 half-chains per (d,s) -----------
// All global reads contiguous (xcT/zT scan-tiled, ssm L2-shared). Half B has
// zero-init state, tracks P,K; true contribution = yaccB + h_endA * K.
__global__ __launch_bounds__(1024) void scan_full_kernel(
    const bf16* __restrict__ xcT, const bf16* __restrict__ zTg,
    const float* __restrict__ ssm,
    const float* __restrict__ dtw, const float* __restrict__ dtb,
    const float* __restrict__ A_log, const float* __restrict__ Dd,
    float* __restrict__ ybar)
{
  __shared__ __align__(16) unsigned short xct[2][32][32];
  __shared__ __align__(16) unsigned short zt[2][32][32];
  __shared__ __align__(8)  float BC[2][32][34];   // [t][2s]=B, [t][2s+1]=C
  __shared__ float dts[2][32];
  __shared__ __align__(16) float cgd[2][32][32][4]; // {c0, gate, de, 0}
  __shared__ float xdp_s[32][32];
  __shared__ float hendA[32][16];
  __shared__ float ybh[2][32];

  int dgrp = blockIdx.x, b = blockIdx.y;
  int tid = threadIdx.x;
  int bb = b << 9;
  size_t trow = ((size_t)(b * 16 + dgrp)) * 512;  // base t-row in xcT/zT

  // scan-role mapping
  int s  = tid & 15;
  int dp = (tid >> 4) & 31;
  int qh = tid >> 9;               // half: 0 -> t in [0,256), 1 -> [256,512)
  int dS = dgrp * 32 + dp;
  float As  = -__expf(A_log[dS * 16 + s]);
  // precompute-role mapping
  int d2 = tid & 31, r32 = (tid >> 5) & 31;
  int dC = dgrp * 32 + d2;
  float wdC = dtw[dC], bdC = dtb[dC];

  float h = 0.f, yacc = 0.f, P = 1.f, K = 0.f, xdp = 0.f;

  for (int p = 0; p < 8; ++p) {
    __syncthreads();
    // ---- stage xc/z tiles (contiguous) + BC/dt ----
    if (tid < 512) {
      int kind = tid >> 8;           // 0: xc, 1: z
      int q = (tid >> 7) & 1;
      int e = tid & 127;
      int row = e >> 2, c4 = e & 3;
      int t = q * 256 + p * 32 + row;
      const unsigned short* src = (const unsigned short*)(kind ? zTg : xcT);
      uint4 v = *(const uint4*)(src + (trow + t) * 32 + c4 * 8);
      if (kind) *(uint4*)&zt[q][row][c4 * 8] = v;
      else      *(uint4*)&xct[q][row][c4 * 8] = v;
    } else {
      int t2 = tid - 512;
      int q = t2 >> 8;
      int r = (t2 >> 3) & 31, l8 = t2 & 7;
      int t0q = q * 256 + p * 32;
      const float* srow = ssm + (size_t)(bb + t0q + r) * 64;
      float4 v = *(const float4*)(srow + l8 * 4);
      int cc = l8 * 4;
      if (cc < 16) {
        BC[q][r][cc*2]   = v.x; BC[q][r][cc*2+2] = v.y;
        BC[q][r][cc*2+4] = v.z; BC[q][r][cc*2+6] = v.w;
      } else {
        int c2 = cc - 16;
        BC[q][r][c2*2+1] = v.x; BC[q][r][c2*2+3] = v.y;
        BC[q][r][c2*2+5] = v.z; BC[q][r][c2*2+7] = v.w;
      }
      if (l8 == 0) dts[q][r] = srow[32];
    }
    __syncthreads();
    // ---- precompute c0/gate/de per (t,d), both halves; D-term partial ----
    #pragma unroll
    for (int q = 0; q < 2; ++q) {
      float xc = bfu(xct[q][r32][d2]);
      float gt = silu_f(bfu(zt[q][r32][d2]));
      float de = softplus_f(dts[q][r32] * wdC + bdC);
      xdp += xc * gt;
      float4 pk; pk.x = de * xc; pk.y = gt; pk.z = de; pk.w = 0.f;
      *(float4*)&cgd[q][r32][d2][0] = pk;
    }
    __syncthreads();
    // ---- scan 32 steps on own half ----
    #pragma unroll
    for (int i = 0; i < 32; ++i) {
      float4 cg = *(const float4*)&cgd[qh][i][dp][0];
      float2 bc = *(const float2*)&BC[qh][i][s * 2];
      float a = __expf(As * cg.z);
      h = a * h + cg.x * bc.x;
      float w = bc.y * cg.y;
      yacc += h * w;
      if (qh) { P *= a; K += P * w; }   // wave-uniform branch
    }
  }
  // ---- combine halves + reduce ----
  xdp_s[r32][d2] = xdp;
  if (qh == 0) hendA[dp][s] = h;
  __syncthreads();
  if (qh == 1) yacc += hendA[dp][s] * K;
  yacc += __shfl_xor(yacc, 1, 64);
  yacc += __shfl_xor(yacc, 2, 64);
  yacc += __shfl_xor(yacc, 4, 64);
  yacc += __shfl_xor(yacc, 8, 64);
  if (s == 0) ybh[qh][dp] = yacc;
  __syncthreads();
  if (qh == 0 && s == 0) {
    float xds = 0.f;
    #pragma unroll
    for (int k = 0; k < 32; ++k) xds += xdp_s[k][dp];
    ybar[b * 512 + dS] = ybh[0][dp] + ybh[1][dp] + Dd[dS] * xds;
  }
}

// ---------------- K4: head (hp_part fold + ybar @ Wout^T + MLP) -------------
__global__ __launch_bounds__(256) void head_kernel(
    const float* __restrict__ hp_part, const float* __restrict__ ybar,
    const float* __restrict__ w_out,
    const float* __restrict__ midw, const float* __restrict__ midb,
    const float* __restrict__ mng, const float* __restrict__ mnb,
    const float* __restrict__ bng, const float* __restrict__ bnb,
    const float* __restrict__ f1w, const float* __restrict__ f1b,
    const float* __restrict__ f2w, const float* __restrict__ f2b,
    float* __restrict__ out)
{
  __shared__ float red[4];
  __shared__ __align__(16) float yb[512];
  __shared__ __align__(16) float shp[256];
  __shared__ __align__(16) float sh[256];
  __shared__ __align__(16) float sh2[128];
  int b = blockIdx.x, j = threadIdx.x;
  yb[j]       = ybar[b * 512 + j];
  yb[256 + j] = ybar[b * 512 + 256 + j];
  float hv = 0.f;
  #pragma unroll
  for (int p = 0; p < NPART; ++p)
    hv += hp_part[(size_t)p * 4096 + b * 256 + j];
  __syncthreads();
  // ssm-path contribution: (1/512) * Wout[j] . ybar[b]
  {
    float acc2 = 0.f;
    const float4* wr = (const float4*)(w_out + j * 512);
    const float4* yv = (const float4*)yb;
    #pragma unroll 4
    for (int k = 0; k < 128; ++k) {
      float4 w = wr[k], x = yv[k];
      acc2 += w.x * x.x + w.y * x.y + w.z * x.z + w.w * x.w;
    }
    hv += acc2 * (1.f / 512.f);
  }
  shp[j] = hv;
  __syncthreads();
  float acc = midb[j];
  {
    const float4* mw = (const float4*)(midw + j * 256);
    const float4* sv = (const float4*)shp;
    #pragma unroll 4
    for (int k = 0; k < 64; ++k) {
      float4 w = mw[k], xv = sv[k];
      acc += w.x * xv.x + w.y * xv.y + w.z * xv.z + w.w * xv.w;
    }
  }
  float s1 = block_sum256(acc, red);
  float s2 = block_sum256(acc * acc, red);
  float mean = s1 * (1.f / 256.f);
  float var  = s2 * (1.f / 256.f) - mean * mean;
  float h2 = gelu_f((acc - mean) * rsqrtf(var + 1e-5f) * mng[j] + mnb[j]);
  float hbn = h2 * rsqrtf(1.0f + 1e-5f) * bng[j] + bnb[j];
  sh[j] = hbn;
  __syncthreads();
  if (j < 128) {
    float a2 = f1b[j];
    const float4* fw = (const float4*)(f1w + j * 256);
    const float4* sv = (const float4*)sh;
    #pragma unroll 4
    for (int k = 0; k < 64; ++k) {
      float4 w = fw[k], xv = sv[k];
      a2 += w.x * xv.x + w.y * xv.y + w.z * xv.z + w.w * xv.w;
    }
    sh2[j] = gelu_f(a2);
  }
  __syncthreads();
  if (j == 0) {
    float o = f2b[0];
    const float4* fw = (const float4*)f2w;
    const float4* sv = (const float4*)sh2;
    for (int k = 0; k < 32; ++k) {
      float4 w = fw[k], xv = sv[k];
      o += w.x * xv.x + w.y * xv.y + w.z * xv.z + w.w * xv.w;
    }
    out[b] = o;
  }
}

// ---------------- launch ----------------
extern "C" void kernel_launch(void* const* d_in, const int* in_sizes, int n_in,
                              void* d_out, int out_size, void* d_ws, size_t ws_size,
                              hipStream_t stream)
{
  const float* cir        = (const float*)d_in[0];
  const float* aux        = (const float*)d_in[1];
  const float* cir_proj_w = (const float*)d_in[2];
  const float* cir_norm_g = (const float*)d_in[3];
  const float* cir_norm_b = (const float*)d_in[4];
  const float* aux_proj_w = (const float*)d_in[5];
  const float* aux_norm_g = (const float*)d_in[6];
  const float* aux_norm_b = (const float*)d_in[7];
  const float* m_norm_g   = (const float*)d_in[8];
  const float* m_norm_b   = (const float*)d_in[9];
  const float* in_proj_w  = (const float*)d_in[10];
  const float* conv_w     = (const float*)d_in[11];
  const float* conv_b     = (const float*)d_in[12];
  const float* x_proj_w   = (const float*)d_in[13];
  const float* dt_proj_w  = (const float*)d_in[14];
  const float* dt_proj_b  = (const float*)d_in[15];
  const float* A_log      = (const float*)d_in[16];
  const float* Dd         = (const float*)d_in[17];
  const float* out_proj_w = (const float*)d_in[18];
  const float* mid_w      = (const float*)d_in[19];
  const float* mid_b      = (const float*)d_in[20];
  const float* mid_norm_g = (const float*)d_in[21];
  const float* mid_norm_b = (const float*)d_in[22];
  const float* bn_g       = (const float*)d_in[23];
  const float* bn_b       = (const float*)d_in[24];
  const float* fc1_w      = (const float*)d_in[25];
  const float* fc1_b      = (const float*)d_in[26];
  const float* fc2_w      = (const float*)d_in[27];
  const float* fc2_b      = (const float*)d_in[28];
  float* out = (float*)d_out;

  float* ws      = (float*)d_ws;
  bf16*  xbf     = (bf16*)ws;                        // BT*512 bf16 -> 2,097,152 f
  bf16*  zTg     = (bf16*)(ws + 2097152);            // BT*512 bf16 -> 2,097,152 f
  bf16*  xcT     = (bf16*)(ws + 4194304);            // BT*512 bf16 -> 2,097,152 f
  float* ssm     = ws + 6291456;                     // BT*64 f = 524,288
  bf16*  w_inbf  = (bf16*)(ssm + 524288);            // 262,144 bf16 -> 131,072 f
  bf16*  wpadbf  = (bf16*)((float*)w_inbf + 131072); // 32,768 bf16 -> 16,384 f
  bf16*  cpwTbf  = (bf16*)((float*)wpadbf + 16384);  // 8,192 bf16 -> 4,096 f
  float* haux    = (float*)cpwTbf + 4096;            // 4,096 f
  float* hp_part = haux + 4096;                      // NPART*4096 = 131,072 f
  float* ybar    = hp_part + 131072;                 // 8,192 f

  prep_kernel<<<1184, 256, 0, stream>>>(aux, aux_proj_w, aux_norm_g, aux_norm_b,
                                        in_proj_w, x_proj_w, cir_proj_w,
                                        w_inbf, wpadbf, cpwTbf, haux);
  row_inproj_kernel<<<512, 512, 0, stream>>>(cir, cpwTbf, cir_norm_g, cir_norm_b,
                                             m_norm_g, m_norm_b, haux, w_inbf,
                                             xbf, zTg, hp_part);
  conv_xproj_kernel<<<dim3(16, Bsz), 512, 0, stream>>>(xbf, wpadbf, conv_w, conv_b,
                                                       ssm, xcT);
  scan_full_kernel<<<dim3(16, Bsz), 1024, 0, stream>>>(xcT, zTg, ssm,
                                                       dt_proj_w, dt_proj_b,
                                                       A_log, Dd, ybar);
  head_kernel<<<16, 256, 0, stream>>>(hp_part, ybar, out_proj_w,
                                      mid_w, mid_b, mid_norm_g, mid_norm_b,
                                      bn_g, bn_b, fc1_w, fc1_b, fc2_w, fc2_b, out);
}